// Round 1
// baseline (346.410 us; speedup 1.0000x reference)
//
#include <hip/hip_runtime.h>

#define BG   8
#define NN   50000
#define DEG  16
#define DD   64
#define CC   128

// ws layout (floats):
// [0..511]       h[8][64]
// [512..519]     c_obj[8]
// [520..527]     c_rel[8]
// [528..528+NN)  s_n[NN]

__global__ void k_setup(const float* __restrict__ IH, const float* __restrict__ W_in,
                        const float* __restrict__ W_obj, const float* __restrict__ W_rel,
                        float* __restrict__ ws) {
    int t = threadIdx.x;              // 0..511
    int g = t >> 6, d = t & 63;
    float acc = 0.f;
    #pragma unroll 8
    for (int c = 0; c < CC; ++c) acc += IH[g * CC + c] * W_in[d * CC + c];
    ws[t] = acc;                      // h[g][d]
    __syncthreads();
    if (t < 16) {
        int gg = t & 7;
        const float* w = (t < 8) ? W_obj : W_rel;   // first 64 coeffs act on h
        float s = 0.f;
        #pragma unroll 8
        for (int d2 = 0; d2 < DD; ++d2) s += ws[gg * DD + d2] * w[d2];
        ws[512 + t] = s;              // c_obj at 512+g, c_rel at 520+g
    }
}

__global__ void k_sn(const float* __restrict__ F_n, const int* __restrict__ node_graph,
                     const float* __restrict__ W_obj, const float* __restrict__ ws,
                     float* __restrict__ s_n) {
    int i = blockIdx.x * blockDim.x + threadIdx.x;
    if (i >= NN) return;
    const float4* f4 = (const float4*)(F_n + (long)i * DD);
    const float4* w4 = (const float4*)(W_obj + DD);
    float acc = 0.f;
    #pragma unroll
    for (int k = 0; k < DD / 4; ++k) {
        float4 a = f4[k], b = w4[k];
        acc += a.x * b.x + a.y * b.y + a.z * b.z + a.w * b.w;
    }
    s_n[i] = acc + ws[512 + node_graph[i]];
}

__device__ __forceinline__ float wave_sum(float v) {
    #pragma unroll
    for (int off = 32; off; off >>= 1) v += __shfl_xor(v, off, 64);
    return v;
}

__global__ __launch_bounds__(256, 4) void k_main(
    const float* __restrict__ F_n, const float* __restrict__ F_e,
    const int* __restrict__ src, const int* __restrict__ node_graph,
    const float* __restrict__ W_rel, const float* __restrict__ W_phi,
    const float* __restrict__ ws, const float* __restrict__ s_n,
    float* __restrict__ out) {
    __shared__ float W2[DD][132];     // W_phi, row-padded: bank = (lane*4+c)%32 -> conflict-free b128
    __shared__ float U[4][2 * DD];    // per-wave concat([agg, F_n[i]])

    int tid = threadIdx.x;
    // stage W_phi -> LDS (coalesced float4 reads; 8192 floats)
    #pragma unroll
    for (int it = 0; it < 8; ++it) {
        int idx4 = (it * 256 + tid) * 4;
        float4 v = *(const float4*)(W_phi + idx4);
        int d = idx4 >> 7, c = idx4 & 127;
        *(float4*)&W2[d][c] = v;
    }

    int wave = tid >> 6, lane = tid & 63;
    int i = blockIdx.x * 4 + wave;            // grid is exactly NN/4 blocks
    const float wrel = W_rel[DD + lane];
    const long ibase = (long)i * DD;
    float fn_i = F_n[ibase + lane];
    const int eb = i * DEG;                   // edges for node i are [16i,16i+16) (dst=repeat(arange))

    // dominant stream: 16 contiguous F_e rows
    float fe[DEG];
    const float* fep = F_e + (long)eb * DD + lane;
    #pragma unroll
    for (int k = 0; k < DEG; ++k) fe[k] = fep[k * DD];

    // gather src rows + their precomputed scores
    float sn[DEG], fns[DEG];
    const int* sp = src + eb;
    #pragma unroll
    for (int k = 0; k < DEG; ++k) {
        int s = sp[k];
        sn[k] = s_n[s];
        fns[k] = F_n[(long)s * DD + lane];
    }

    // s_e = c_rel[g] + <F_e, W_rel_hi>  (16 wave reductions)
    float crel = ws[520 + node_graph[i]];
    float se[DEG];
    #pragma unroll
    for (int k = 0; k < DEG; ++k) {
        se[k] = wave_sum(fe[k] * wrel) + crel;
    }

    // softmax over 32 messages
    float m = -1e30f;
    #pragma unroll
    for (int k = 0; k < DEG; ++k) { m = fmaxf(m, se[k]); m = fmaxf(m, sn[k]); }
    float denom = 0.f, agg = 0.f;
    #pragma unroll
    for (int k = 0; k < DEG; ++k) {
        float en = __expf(sn[k] - m);
        denom += en;
        agg = fmaf(fns[k], en, agg);
        float ee = __expf(se[k] - m);
        denom += ee;
        agg = fmaf(fe[k], ee, agg);
    }
    agg /= denom;

    // phi matvec: F_new[i][lane] = relu( sum_c W_phi[lane][c] * u[c] )
    U[wave][lane] = agg;
    U[wave][DD + lane] = fn_i;
    __syncthreads();                          // W2 ready (U is same-wave, covered too)

    float acc = 0.f;
    #pragma unroll
    for (int c = 0; c < 2 * DD; c += 4) {
        float4 u4 = *(const float4*)&U[wave][c];      // uniform addr -> LDS broadcast
        float4 w4 = *(const float4*)&W2[lane][c];     // conflict-free b128
        acc = fmaf(w4.x, u4.x, acc);
        acc = fmaf(w4.y, u4.y, acc);
        acc = fmaf(w4.z, u4.z, acc);
        acc = fmaf(w4.w, u4.w, acc);
    }
    acc = fmaxf(acc, 0.f);
    out[ibase + lane] = acc;

    // io_mask = (row sum != 0)
    float s = wave_sum(acc);
    if (lane == 0) out[(long)NN * DD + i] = (s != 0.f) ? 1.f : 0.f;
}

extern "C" void kernel_launch(void* const* d_in, const int* in_sizes, int n_in,
                              void* d_out, int out_size, void* d_ws, size_t ws_size,
                              hipStream_t stream) {
    const float* IH     = (const float*)d_in[0];
    const float* F_n    = (const float*)d_in[1];
    const float* F_e    = (const float*)d_in[2];
    const int*   src    = (const int*)d_in[3];
    // d_in[4] = dst (structure known: repeat(arange(N),16)), d_in[6] = edge_graph (== node_graph[dst])
    const int*   ngr    = (const int*)d_in[5];
    const float* W_in   = (const float*)d_in[7];
    const float* W_obj  = (const float*)d_in[8];
    const float* W_rel  = (const float*)d_in[9];
    const float* W_phi  = (const float*)d_in[10];
    float* out = (float*)d_out;
    float* ws  = (float*)d_ws;
    float* s_n = ws + 528;

    k_setup<<<1, 512, 0, stream>>>(IH, W_in, W_obj, W_rel, ws);
    k_sn<<<(NN + 255) / 256, 256, 0, stream>>>(F_n, ngr, W_obj, ws, s_n);
    k_main<<<NN / 4, 256, 0, stream>>>(F_n, F_e, src, ngr, W_rel, W_phi, ws, s_n, out);
}